// Round 7
// baseline (265.914 us; speedup 1.0000x reference)
//
#include <hip/hip_runtime.h>

typedef unsigned short u16;
typedef unsigned int u32;
typedef __attribute__((ext_vector_type(8))) short bf16x8;
typedef __attribute__((ext_vector_type(4))) float f32x4;

#define MFMA16(a, b, c) __builtin_amdgcn_mfma_f32_16x16x32_bf16((a), (b), (c), 0, 0, 0)

constexpr int D = 1024;       // d_model
constexpr int NH = 16;        // heads
constexpr int HD = 64;        // head dim
constexpr int BB = 4;         // batch
constexpr int SS = 2048;      // seq len
constexpr int BH = BB * NH;   // 64
constexpr int MTOK = BB * SS; // 8192
constexpr float SCALE_LOG2E = 0.125f * 1.44269504088896340736f; // HD^-0.5 * log2(e)

__device__ __forceinline__ u16 f32_bf16(float f) {
  union { float f; u32 u; } v; v.f = f;
  u32 u = v.u;
  u += 0x7FFFu + ((u >> 16) & 1u); // RNE
  return (u16)(u >> 16);
}

// single-instruction transcendental / convert paths (avoid ocml calls)
__device__ __forceinline__ float exp2_fast(float x) {
  float r; asm("v_exp_f32 %0, %1" : "=v"(r) : "v"(x)); return r;
}
__device__ __forceinline__ u16 cvt_bf16_1(float f) {
  u32 r; asm("v_cvt_pk_bf16_f32 %0, %1, %1" : "=v"(r) : "v"(f)); return (u16)r;
}

__device__ __forceinline__ void gload_lds16(const void* g, u16* l) {
  __builtin_amdgcn_global_load_lds(
      (const __attribute__((address_space(1))) u32*)g,
      (__attribute__((address_space(3))) u32*)l, 16, 0, 0);
}

// ---------------- fp32 -> bf16 elementwise convert ----------------
__global__ __launch_bounds__(256)
void cvt_bf16(const float* __restrict__ in, u16* __restrict__ out, int n4) {
  int i = blockIdx.x * 256 + threadIdx.x;
  const int stride = gridDim.x * 256;
  for (; i < n4; i += stride) {
    float4 v = reinterpret_cast<const float4*>(in)[i];
    u32 lo = (u32)f32_bf16(v.x) | ((u32)f32_bf16(v.y) << 16);
    u32 hi = (u32)f32_bf16(v.z) | ((u32)f32_bf16(v.w) << 16);
    reinterpret_cast<uint2*>(out)[i] = make_uint2(lo, hi);
  }
}

// ---------------- fp32 [R][C] -> bf16 [C][R] transpose ----------------
__global__ __launch_bounds__(256)
void transpose_bf16(const float* __restrict__ in, u16* __restrict__ out, int R, int C) {
  __shared__ float tile[32][33];
  const int c0 = blockIdx.x * 32, r0 = blockIdx.y * 32;
  const int tx = threadIdx.x, ty = threadIdx.y;
#pragma unroll
  for (int i = 0; i < 4; i++)
    tile[ty + 8 * i][tx] = in[(size_t)(r0 + ty + 8 * i) * C + c0 + tx];
  __syncthreads();
#pragma unroll
  for (int i = 0; i < 4; i++)
    out[(size_t)(c0 + ty + 8 * i) * R + r0 + tx] = f32_bf16(tile[tx][ty + 8 * i]);
}

// ---------------- bf16 GEMM: C[M][N] = A[M][K] * Bt[N][K]^T + bias ----------------
// 1D grid with bijective XCD swizzle (nwg % 8 == 0): each XCD gets a contiguous
// chunk of the (n-major) tile space -> B-panels resident in its L2.
// MODE 0: scatter into Q (pre-scaled by SCALE*log2e) [BH][S][64], K [BH][S][64],
//         Vt [BH][64][S] (bf16)
// MODE 1: fp32 out [M][N]
template <int MODE>
__global__ __launch_bounds__(256)
void gemm_bf16(const u16* __restrict__ A, const u16* __restrict__ Bt,
               const float* __restrict__ bias,
               u16* __restrict__ q_out, u16* __restrict__ k_out,
               u16* __restrict__ vt_out, float* __restrict__ f_out,
               int M, int N, int K) {
  constexpr int BK = 32;
  __shared__ u16 lds_a[128 * BK];
  __shared__ u16 lds_b[128 * BK];
  const int nm = M >> 7;
  const int nwg = nm * (N >> 7);
  const int bid = blockIdx.x;
  const int wk = (bid & 7) * (nwg >> 3) + (bid >> 3); // XCD-contiguous work chunks
  const int m0 = (wk % nm) * 128;
  const int n0 = (wk / nm) * 128;
  const int t = threadIdx.x;
  const int lane = t & 63;
  const int w = t >> 6;
  const int wr = w >> 1, wc = w & 1;        // 2x2 wave grid, 64x64 per wave
  const int fr = lane & 15, fq = lane >> 4; // fragment row/col group

  const u16* ga0 = A + (size_t)(m0 + (t >> 2)) * K + (t & 3) * 8;
  const u16* ga1 = ga0 + (size_t)64 * K;
  const u16* gb0 = Bt + (size_t)(n0 + (t >> 2)) * K + (t & 3) * 8;
  const u16* gb1 = gb0 + (size_t)64 * K;
  u16* la0 = lds_a + t * 8;
  u16* la1 = lds_a + (t + 256) * 8;
  u16* lb0 = lds_b + t * 8;
  u16* lb1 = lds_b + (t + 256) * 8;

  f32x4 acc[4][4] = {};

  for (int k0 = 0; k0 < K; k0 += BK) {
    __syncthreads();
    gload_lds16(ga0, la0);
    gload_lds16(ga1, la1);
    gload_lds16(gb0, lb0);
    gload_lds16(gb1, lb1);
    ga0 += BK; ga1 += BK; gb0 += BK; gb1 += BK;
    __syncthreads();
    bf16x8 af[4], bfr[4];
#pragma unroll
    for (int i = 0; i < 4; i++)
      af[i] = *reinterpret_cast<const bf16x8*>(lds_a + (wr * 64 + i * 16 + fr) * BK + fq * 8);
#pragma unroll
    for (int i = 0; i < 4; i++)
      bfr[i] = *reinterpret_cast<const bf16x8*>(lds_b + (wc * 64 + i * 16 + fr) * BK + fq * 8);
#pragma unroll
    for (int i = 0; i < 4; i++)
#pragma unroll
      for (int j = 0; j < 4; j++)
        acc[i][j] = MFMA16(af[i], bfr[j], acc[i][j]);
  }

#pragma unroll
  for (int i = 0; i < 4; i++) {
#pragma unroll
    for (int j = 0; j < 4; j++) {
      const int ncol = n0 + wc * 64 + j * 16 + fr;
      const float bs = bias[ncol];
#pragma unroll
      for (int r = 0; r < 4; r++) {
        const int mrow = m0 + wr * 64 + i * 16 + fq * 4 + r;
        const float vv = acc[i][j][r] + bs;
        if (MODE == 0) {
          const int which = ncol >> 10;
          const int rem = ncol & 1023;
          const int hh = rem >> 6, dd = rem & 63;
          const int bb = mrow >> 11, ss = mrow & 2047;
          const int bh = bb * 16 + hh;
          if (which == 0)
            q_out[((size_t)bh * SS + ss) * HD + dd] = f32_bf16(vv * SCALE_LOG2E);
          else if (which == 1)
            k_out[((size_t)bh * SS + ss) * HD + dd] = f32_bf16(vv);
          else
            vt_out[((size_t)bh * HD + dd) * SS + ss] = f32_bf16(vv);
        } else {
          f_out[(size_t)mrow * N + ncol] = vv;
        }
      }
    }
  }
}

// ---------------- causal flash attention ----------------
// Q (pre-scaled), K: [BH][S][64] bf16 ; Vt: [BH][64][S] bf16 ; vals: [B][S][D] bf16
// Block = q-tile PAIR (pi, 31-pi): exactly 33 kv-tiles per block (uniform work).
// XCD swizzle: 1D grid, each XCD owns 8 heads (8 x 512KB K/V = 4MB = L2-resident).
// K/V tiles double-buffered in LDS (XOR-swizzled), staged with global_load_lds.
// Softmax: deferred row-sum, defer-max rescale (THR=8), single-instr exp2/cvt.
__global__ __launch_bounds__(256)
void attn_fwd(const u16* __restrict__ Qb, const u16* __restrict__ Kb,
              const u16* __restrict__ Vt, u16* __restrict__ vals) {
  const int bid = blockIdx.x;                 // 0..1023
  const int wk = (bid & 7) * 128 + (bid >> 3); // XCD-contiguous chunks of 128
  const int bh = wk >> 4;                      // 8 heads per XCD chunk
  const int pi = wk & 15;
  const u16* Qp = Qb + (size_t)bh * SS * HD;
  const char* Kp = (const char*)(Kb + (size_t)bh * SS * HD);
  const char* Vp = (const char*)(Vt + (size_t)bh * HD * SS);
  const int t = threadIdx.x, lane = t & 63, w = t >> 6;
  const int fr = lane & 15, fq = lane >> 4;
  const int swz = (fr & 7) << 4; // row&7 == fr&7 for all fragment rows used below

  __shared__ u16 kbuf[2][4096]; // [64 rows][128B] swizzled, 8KB each
  __shared__ u16 vbuf[2][4096]; // [64 d-rows][128B keys] swizzled
  __shared__ u16 plds[4][16][72];
  u16* myp = &plds[w][0][0];

  const int qtA = pi, qtB = 31 - pi;
  const int nA = qtA + 1, nTot = nA + qtB + 1; // == 33

  const int lin0 = t * 16; // staging byte offset, round 0

  // loop-invariant swizzled LDS fragment offsets (static-indexed -> registers)
  int offKV[8];
#pragma unroll
  for (int kf = 0; kf < 4; kf++)
#pragma unroll
    for (int kk = 0; kk < 2; kk++)
      offKV[kf * 2 + kk] = (kf * 16 + fr) * 128 + ((kk * 64 + fq * 16) ^ swz);

  bf16x8 aq[2];
  {
    const int qbase = qtA * 64 + w * 16;
#pragma unroll
    for (int kk = 0; kk < 2; kk++)
      aq[kk] = *reinterpret_cast<const bf16x8*>(Qp + (size_t)(qbase + fr) * HD + kk * 32 + fq * 8);
  }

  f32x4 o[4] = {};
  float mrun[4], lpart[4];
#pragma unroll
  for (int j = 0; j < 4; j++) { mrun[j] = -3e38f; lpart[j] = 0.f; }

#define STAGE(bufi, kvt_)                                                     \
  {                                                                           \
    _Pragma("unroll")                                                         \
    for (int r = 0; r < 2; r++) {                                             \
      const int lin = lin0 + r * 4096;                                        \
      const int row = lin >> 7, colb = lin & 127;                             \
      const int scol = colb ^ ((row & 7) << 4);                               \
      gload_lds16(Kp + (size_t)((kvt_) * 64 + row) * 128 + scol,              \
                  &kbuf[bufi][lin >> 1]);                                     \
      gload_lds16(Vp + (size_t)row * 4096 + (kvt_) * 128 + scol,              \
                  &vbuf[bufi][lin >> 1]);                                     \
    }                                                                         \
  }

  auto write_out = [&](int qt) {
    const int b_ = bh >> 4, h_ = bh & 15;
    const int qb = qt * 64 + w * 16;
    float linv[4];
#pragma unroll
    for (int j = 0; j < 4; j++) {
      float rs = lpart[j];
#pragma unroll
      for (int off = 1; off < 16; off <<= 1)
        rs += __shfl_xor(rs, off, 64);
      linv[j] = 1.f / rs;
    }
#pragma unroll
    for (int df = 0; df < 4; df++)
#pragma unroll
      for (int j = 0; j < 4; j++) {
        const float vv = o[df][j] * linv[j];
        const int qg = qb + fq * 4 + j;
        vals[((size_t)(b_ * SS + qg)) * D + h_ * HD + df * 16 + fr] = cvt_bf16_1(vv);
      }
  };

  int cur = 0;
  STAGE(0, 0);
  asm volatile("s_waitcnt vmcnt(0)" ::: "memory");
  __syncthreads();

  for (int ti = 0; ti < nTot; ++ti) {
    const bool segB = ti >= nA;
    const int kvt = segB ? ti - nA : ti;
    const int qt = segB ? qtB : qtA;
    // prefetch next kv tile (kv tiles are qt-independent, so the pipeline
    // runs flat across the segment boundary)
    if (ti + 1 < nTot) {
      const int nk = (ti + 1 >= nA) ? (ti + 1 - nA) : (ti + 1);
      STAGE(cur ^ 1, nk);
    }
    if (ti == nA) { // segment switch: flush A, reset state for B
      write_out(qtA);
      const int qbase = qtB * 64 + w * 16;
#pragma unroll
      for (int kk = 0; kk < 2; kk++)
        aq[kk] = *reinterpret_cast<const bf16x8*>(Qp + (size_t)(qbase + fr) * HD + kk * 32 + fq * 8);
#pragma unroll
      for (int j = 0; j < 4; j++) { mrun[j] = -3e38f; lpart[j] = 0.f; }
#pragma unroll
      for (int df = 0; df < 4; df++) o[df] = f32x4{0.f, 0.f, 0.f, 0.f};
    }

    const char* kb = (const char*)kbuf[cur];
    const char* vb = (const char*)vbuf[cur];

    // S = Q K^T (Q pre-scaled by SCALE*log2e -> scores already in log2 units)
    f32x4 sc[4] = {};
#pragma unroll
    for (int kf = 0; kf < 4; kf++) {
#pragma unroll
      for (int kk = 0; kk < 2; kk++) {
        bf16x8 bk = *reinterpret_cast<const bf16x8*>(kb + offKV[kf * 2 + kk]);
        sc[kf] = MFMA16(aq[kk], bk, sc[kf]);
      }
    }
    // causal mask: diagonal tile only
    if (kvt == qt) {
#pragma unroll
      for (int kf = 0; kf < 4; kf++)
#pragma unroll
        for (int j = 0; j < 4; j++) {
          const int keyl = kf * 16 + fr;
          const int ql = w * 16 + fq * 4 + j;
          if (keyl > ql) sc[kf][j] = -3e38f;
        }
    }
    // online softmax: tile max per row (rows live across fr lanes)
    float mj[4];
#pragma unroll
    for (int j = 0; j < 4; j++) {
      float m = fmaxf(fmaxf(sc[0][j], sc[1][j]), fmaxf(sc[2][j], sc[3][j]));
#pragma unroll
      for (int off = 1; off < 16; off <<= 1)
        m = fmaxf(m, __shfl_xor(m, off, 64));
      mj[j] = m;
    }
    // defer-max: only rescale when a row max grew by > 8 (log2 units)
    const bool need = (mj[0] > mrun[0] + 8.f) | (mj[1] > mrun[1] + 8.f) |
                      (mj[2] > mrun[2] + 8.f) | (mj[3] > mrun[3] + 8.f);
    if (__any((int)need)) {
#pragma unroll
      for (int j = 0; j < 4; j++) {
        const float mnew = fmaxf(mrun[j], mj[j]);
        const float alpha = exp2_fast(mrun[j] - mnew);
        mrun[j] = mnew;
        lpart[j] *= alpha;
#pragma unroll
        for (int df = 0; df < 4; df++) o[df][j] *= alpha;
      }
    }
    // P = exp2(S - m); accumulate per-lane partial row-sums (reduced at flush)
#pragma unroll
    for (int j = 0; j < 4; j++) {
#pragma unroll
      for (int kf = 0; kf < 4; kf++) {
        const float p = exp2_fast(sc[kf][j] - mrun[j]);
        sc[kf][j] = p;
        lpart[j] += p;
      }
    }
    // P -> per-wave LDS (bf16), then read A-fragments (wave-internal DS ordering)
#pragma unroll
    for (int kf = 0; kf < 4; kf++)
#pragma unroll
      for (int j = 0; j < 4; j++)
        myp[(fq * 4 + j) * 72 + kf * 16 + fr] = cvt_bf16_1(sc[kf][j]);
    bf16x8 pa[2];
#pragma unroll
    for (int kk = 0; kk < 2; kk++)
      pa[kk] = *reinterpret_cast<const bf16x8*>(myp + fr * 72 + kk * 32 + fq * 8);
    // O += P V  (V tile in LDS: [d-row][key] swizzled; same offsets as K)
#pragma unroll
    for (int df = 0; df < 4; df++) {
#pragma unroll
      for (int kk = 0; kk < 2; kk++) {
        bf16x8 bv = *reinterpret_cast<const bf16x8*>(vb + offKV[df * 2 + kk]);
        o[df] = MFMA16(pa[kk], bv, o[df]);
      }
    }

    asm volatile("s_waitcnt vmcnt(0)" ::: "memory");
    __syncthreads();
    cur ^= 1;
  }
  write_out(qtB);
#undef STAGE
}

extern "C" void kernel_launch(void* const* d_in, const int* in_sizes, int n_in,
                              void* d_out, int out_size, void* d_ws, size_t ws_size,
                              hipStream_t stream) {
  const float* x = (const float*)d_in[0];
  const float* Wqkv = (const float*)d_in[1];
  const float* bqkv = (const float*)d_in[2];
  const float* Wout = (const float*)d_in[3];
  const float* bout = (const float*)d_in[4];
  float* out = (float*)d_out;

  char* p = (char*)d_ws;
  u16* xb = (u16*)p;    p += (size_t)MTOK * D * 2;       // 16.8 MB
  u16* wqkvT = (u16*)p; p += (size_t)3 * D * D * 2;      // 6.3 MB
  u16* woutT = (u16*)p; p += (size_t)D * D * 2;          // 2.1 MB
  u16* Qb = (u16*)p;    p += (size_t)BH * SS * HD * 2;   // 16.8 MB
  u16* Kb = (u16*)p;    p += (size_t)BH * SS * HD * 2;   // 16.8 MB
  u16* Vt = (u16*)p;    p += (size_t)BH * SS * HD * 2;   // 16.8 MB
  u16* vals = (u16*)p;  p += (size_t)MTOK * D * 2;       // 16.8 MB  (total ~92 MB)

  cvt_bf16<<<2048, 256, 0, stream>>>(x, xb, MTOK * D / 4);
  transpose_bf16<<<dim3(3 * D / 32, D / 32), dim3(32, 8), 0, stream>>>(Wqkv, wqkvT, D, 3 * D);
  transpose_bf16<<<dim3(D / 32, D / 32), dim3(32, 8), 0, stream>>>(Wout, woutT, D, D);
  gemm_bf16<0><<<dim3((MTOK / 128) * (3 * D / 128)), 256, 0, stream>>>(
      xb, wqkvT, bqkv, Qb, Kb, Vt, nullptr, MTOK, 3 * D, D);
  attn_fwd<<<dim3(16 * BH), 256, 0, stream>>>(Qb, Kb, Vt, vals);
  gemm_bf16<1><<<dim3((MTOK / 128) * (D / 128)), 256, 0, stream>>>(
      vals, woutT, bout, nullptr, nullptr, nullptr, out, MTOK, D, D);
}

// Round 8
// 233.694 us; speedup vs baseline: 1.1379x; 1.1379x over previous
//
#include <hip/hip_runtime.h>

typedef unsigned short u16;
typedef unsigned int u32;
typedef __attribute__((ext_vector_type(8))) short bf16x8;
typedef __attribute__((ext_vector_type(4))) float f32x4;

#define MFMA16(a, b, c) __builtin_amdgcn_mfma_f32_16x16x32_bf16((a), (b), (c), 0, 0, 0)

constexpr int D = 1024;       // d_model
constexpr int NH = 16;        // heads
constexpr int HD = 64;        // head dim
constexpr int BB = 4;         // batch
constexpr int SS = 2048;      // seq len
constexpr int BH = BB * NH;   // 64
constexpr int MTOK = BB * SS; // 8192
constexpr float SCALE_LOG2E = 0.125f * 1.44269504088896340736f; // HD^-0.5 * log2(e)

__device__ __forceinline__ u16 f32_bf16(float f) {
  union { float f; u32 u; } v; v.f = f;
  u32 u = v.u;
  u += 0x7FFFu + ((u >> 16) & 1u); // RNE
  return (u16)(u >> 16);
}

// single-instruction transcendental / convert paths (avoid ocml calls)
__device__ __forceinline__ float exp2_fast(float x) {
  float r; asm("v_exp_f32 %0, %1" : "=v"(r) : "v"(x)); return r;
}
__device__ __forceinline__ u16 cvt_bf16_1(float f) {
  u32 r; asm("v_cvt_pk_bf16_f32 %0, %1, %1" : "=v"(r) : "v"(f)); return (u16)r;
}

__device__ __forceinline__ void gload_lds16(const void* g, u16* l) {
  __builtin_amdgcn_global_load_lds(
      (const __attribute__((address_space(1))) u32*)g,
      (__attribute__((address_space(3))) u32*)l, 16, 0, 0);
}

// ---------------- fp32 -> bf16 elementwise convert ----------------
__global__ __launch_bounds__(256)
void cvt_bf16(const float* __restrict__ in, u16* __restrict__ out, int n4) {
  int i = blockIdx.x * 256 + threadIdx.x;
  const int stride = gridDim.x * 256;
  for (; i < n4; i += stride) {
    float4 v = reinterpret_cast<const float4*>(in)[i];
    u32 lo = (u32)f32_bf16(v.x) | ((u32)f32_bf16(v.y) << 16);
    u32 hi = (u32)f32_bf16(v.z) | ((u32)f32_bf16(v.w) << 16);
    reinterpret_cast<uint2*>(out)[i] = make_uint2(lo, hi);
  }
}

// ---------------- fp32 [R][C] -> bf16 [C][R] transpose ----------------
__global__ __launch_bounds__(256)
void transpose_bf16(const float* __restrict__ in, u16* __restrict__ out, int R, int C) {
  __shared__ float tile[32][33];
  const int c0 = blockIdx.x * 32, r0 = blockIdx.y * 32;
  const int tx = threadIdx.x, ty = threadIdx.y;
#pragma unroll
  for (int i = 0; i < 4; i++)
    tile[ty + 8 * i][tx] = in[(size_t)(r0 + ty + 8 * i) * C + c0 + tx];
  __syncthreads();
#pragma unroll
  for (int i = 0; i < 4; i++)
    out[(size_t)(c0 + ty + 8 * i) * R + r0 + tx] = f32_bf16(tile[tx][ty + 8 * i]);
}

// ---------------- bf16 GEMM: C[M][N] = A[M][K] * Bt[N][K]^T + bias ----------------
// 2D grid (round-6 measured-good mapping; the 1D m-major XCD chunking of round 7
// regressed ~20% by streaming all of A through every XCD's L2).
// MODE 0: scatter into Q (pre-scaled by SCALE*log2e) [BH][S][64], K [BH][S][64],
//         Vt [BH][64][S] (bf16)
// MODE 1: fp32 out [M][N]
template <int MODE>
__global__ __launch_bounds__(256)
void gemm_bf16(const u16* __restrict__ A, const u16* __restrict__ Bt,
               const float* __restrict__ bias,
               u16* __restrict__ q_out, u16* __restrict__ k_out,
               u16* __restrict__ vt_out, float* __restrict__ f_out,
               int M, int N, int K) {
  constexpr int BK = 32;
  __shared__ u16 lds_a[128 * BK];
  __shared__ u16 lds_b[128 * BK];
  const int m0 = blockIdx.x * 128;
  const int n0 = blockIdx.y * 128;
  const int t = threadIdx.x;
  const int lane = t & 63;
  const int w = t >> 6;
  const int wr = w >> 1, wc = w & 1;        // 2x2 wave grid, 64x64 per wave
  const int fr = lane & 15, fq = lane >> 4; // fragment row/col group

  const u16* ga0 = A + (size_t)(m0 + (t >> 2)) * K + (t & 3) * 8;
  const u16* ga1 = ga0 + (size_t)64 * K;
  const u16* gb0 = Bt + (size_t)(n0 + (t >> 2)) * K + (t & 3) * 8;
  const u16* gb1 = gb0 + (size_t)64 * K;
  u16* la0 = lds_a + t * 8;
  u16* la1 = lds_a + (t + 256) * 8;
  u16* lb0 = lds_b + t * 8;
  u16* lb1 = lds_b + (t + 256) * 8;

  f32x4 acc[4][4] = {};

  for (int k0 = 0; k0 < K; k0 += BK) {
    __syncthreads();
    gload_lds16(ga0, la0);
    gload_lds16(ga1, la1);
    gload_lds16(gb0, lb0);
    gload_lds16(gb1, lb1);
    ga0 += BK; ga1 += BK; gb0 += BK; gb1 += BK;
    __syncthreads();
    bf16x8 af[4], bfr[4];
#pragma unroll
    for (int i = 0; i < 4; i++)
      af[i] = *reinterpret_cast<const bf16x8*>(lds_a + (wr * 64 + i * 16 + fr) * BK + fq * 8);
#pragma unroll
    for (int i = 0; i < 4; i++)
      bfr[i] = *reinterpret_cast<const bf16x8*>(lds_b + (wc * 64 + i * 16 + fr) * BK + fq * 8);
#pragma unroll
    for (int i = 0; i < 4; i++)
#pragma unroll
      for (int j = 0; j < 4; j++)
        acc[i][j] = MFMA16(af[i], bfr[j], acc[i][j]);
  }

#pragma unroll
  for (int i = 0; i < 4; i++) {
#pragma unroll
    for (int j = 0; j < 4; j++) {
      const int ncol = n0 + wc * 64 + j * 16 + fr;
      const float bs = bias[ncol];
#pragma unroll
      for (int r = 0; r < 4; r++) {
        const int mrow = m0 + wr * 64 + i * 16 + fq * 4 + r;
        const float vv = acc[i][j][r] + bs;
        if (MODE == 0) {
          const int which = ncol >> 10;
          const int rem = ncol & 1023;
          const int hh = rem >> 6, dd = rem & 63;
          const int bb = mrow >> 11, ss = mrow & 2047;
          const int bh = bb * 16 + hh;
          if (which == 0)
            q_out[((size_t)bh * SS + ss) * HD + dd] = f32_bf16(vv * SCALE_LOG2E);
          else if (which == 1)
            k_out[((size_t)bh * SS + ss) * HD + dd] = f32_bf16(vv);
          else
            vt_out[((size_t)bh * HD + dd) * SS + ss] = f32_bf16(vv);
        } else {
          f_out[(size_t)mrow * N + ncol] = vv;
        }
      }
    }
  }
}

// ---------------- causal flash attention ----------------
// Q (pre-scaled), K: [BH][S][64] bf16 ; Vt: [BH][64][S] bf16 ; vals: [B][S][D] bf16
// Block = q-tile PAIR (pi, 31-pi): exactly 33 kv-tiles per block (uniform work).
// XCD swizzle: 1D grid, each XCD owns 8 heads (4MB K/V = L2-resident; verified:
// FETCH 235->24.6 MB).
// Pipeline: 3 LDS buffers, 2-tile-deep prefetch, counted s_waitcnt vmcnt(4) +
// raw s_barrier per tile (never a full drain in steady state, T3/T4-lite).
// Softmax: deferred row-sum, defer-max rescale (THR=8), single-instr exp2/cvt.
__global__ __launch_bounds__(256)
void attn_fwd(const u16* __restrict__ Qb, const u16* __restrict__ Kb,
              const u16* __restrict__ Vt, u16* __restrict__ vals) {
  const int bid = blockIdx.x;                  // 0..1023
  const int wk = (bid & 7) * 128 + (bid >> 3); // XCD-contiguous chunks of 128
  const int bh = wk >> 4;                      // 8 heads per XCD chunk
  const int pi = wk & 15;
  const u16* Qp = Qb + (size_t)bh * SS * HD;
  const char* Kp = (const char*)(Kb + (size_t)bh * SS * HD);
  const char* Vp = (const char*)(Vt + (size_t)bh * HD * SS);
  const int t = threadIdx.x, lane = t & 63, w = t >> 6;
  const int fr = lane & 15, fq = lane >> 4;
  const int swz = (fr & 7) << 4; // row&7 == fr&7 for all fragment rows used below

  __shared__ u16 kbuf[3][4096]; // [64 rows][128B] swizzled, 8KB each
  __shared__ u16 vbuf[3][4096]; // [64 d-rows][128B keys] swizzled
  __shared__ u16 plds[4][16][72];
  u16* myp = &plds[w][0][0];

  const int qtA = pi, qtB = 31 - pi;
  const int nA = qtA + 1, nTot = nA + qtB + 1; // == 33

  const int lin0 = t * 16; // staging byte offset, round 0

  // loop-invariant swizzled LDS fragment offsets (static-indexed -> registers)
  int offKV[8];
#pragma unroll
  for (int kf = 0; kf < 4; kf++)
#pragma unroll
    for (int kk = 0; kk < 2; kk++)
      offKV[kf * 2 + kk] = (kf * 16 + fr) * 128 + ((kk * 64 + fq * 16) ^ swz);

  bf16x8 aq[2];
  {
    const int qbase = qtA * 64 + w * 16;
#pragma unroll
    for (int kk = 0; kk < 2; kk++)
      aq[kk] = *reinterpret_cast<const bf16x8*>(Qp + (size_t)(qbase + fr) * HD + kk * 32 + fq * 8);
  }

  f32x4 o[4] = {};
  float mrun[4], lpart[4];
#pragma unroll
  for (int j = 0; j < 4; j++) { mrun[j] = -3e38f; lpart[j] = 0.f; }

#define STAGE(bufi, kvt_)                                                     \
  {                                                                           \
    _Pragma("unroll")                                                         \
    for (int r = 0; r < 2; r++) {                                             \
      const int lin = lin0 + r * 4096;                                        \
      const int row = lin >> 7, colb = lin & 127;                             \
      const int scol = colb ^ ((row & 7) << 4);                               \
      gload_lds16(Kp + (size_t)((kvt_) * 64 + row) * 128 + scol,              \
                  &kbuf[bufi][lin >> 1]);                                     \
      gload_lds16(Vp + (size_t)row * 4096 + (kvt_) * 128 + scol,              \
                  &vbuf[bufi][lin >> 1]);                                     \
    }                                                                         \
  }

  auto write_out = [&](int qt) {
    const int b_ = bh >> 4, h_ = bh & 15;
    const int qb = qt * 64 + w * 16;
    float linv[4];
#pragma unroll
    for (int j = 0; j < 4; j++) {
      float rs = lpart[j];
#pragma unroll
      for (int off = 1; off < 16; off <<= 1)
        rs += __shfl_xor(rs, off, 64);
      linv[j] = 1.f / rs;
    }
#pragma unroll
    for (int df = 0; df < 4; df++)
#pragma unroll
      for (int j = 0; j < 4; j++) {
        const float vv = o[df][j] * linv[j];
        const int qg = qb + fq * 4 + j;
        vals[((size_t)(b_ * SS + qg)) * D + h_ * HD + df * 16 + fr] = cvt_bf16_1(vv);
      }
  };

  int cur = 0;
  STAGE(0, 0);
  STAGE(1, 1); // nTot >= 2 always; tile index 1 may belong to segment A or B=0
  // note: tile ti's kv index: ti<nA ? ti : ti-nA. For ti=1: if nA==1 (pi==0),
  // kv=0 of segment B. Both map to kv tile "1 if nA>1 else 0":
  // handled below by staging with the generic mapping.
#undef STAGE
#define KVIDX(ti_) ((ti_) >= nA ? (ti_) - nA : (ti_))
#define STAGE(bufi, kvt_)                                                     \
  {                                                                           \
    _Pragma("unroll")                                                         \
    for (int r = 0; r < 2; r++) {                                             \
      const int lin = lin0 + r * 4096;                                        \
      const int row = lin >> 7, colb = lin & 127;                             \
      const int scol = colb ^ ((row & 7) << 4);                               \
      gload_lds16(Kp + (size_t)((kvt_) * 64 + row) * 128 + scol,              \
                  &kbuf[bufi][lin >> 1]);                                     \
      gload_lds16(Vp + (size_t)row * 4096 + (kvt_) * 128 + scol,              \
                  &vbuf[bufi][lin >> 1]);                                     \
    }                                                                         \
  }

  for (int ti = 0; ti < nTot; ++ti) {
    const bool segB = ti >= nA;
    const int kvt = segB ? ti - nA : ti;
    const int qt = segB ? qtB : qtA;

    // wait for tile ti's 4 loads (oldest in the VMEM queue); keep tile ti+1's
    // 4 loads in flight across the barrier (counted vmcnt, T4)
    if (ti + 1 < nTot)
      asm volatile("s_waitcnt vmcnt(4)" ::: "memory");
    else
      asm volatile("s_waitcnt vmcnt(0)" ::: "memory");
    __builtin_amdgcn_s_barrier();
    __builtin_amdgcn_sched_barrier(0);

    if (ti == nA) { // segment switch: flush A, reset state for B
      write_out(qtA);
      const int qbase = qtB * 64 + w * 16;
#pragma unroll
      for (int kk = 0; kk < 2; kk++)
        aq[kk] = *reinterpret_cast<const bf16x8*>(Qp + (size_t)(qbase + fr) * HD + kk * 32 + fq * 8);
#pragma unroll
      for (int j = 0; j < 4; j++) { mrun[j] = -3e38f; lpart[j] = 0.f; }
#pragma unroll
      for (int df = 0; df < 4; df++) o[df] = f32x4{0.f, 0.f, 0.f, 0.f};
    }

    const char* kb = (const char*)kbuf[cur];
    const char* vb = (const char*)vbuf[cur];

    // S = Q K^T (Q pre-scaled by SCALE*log2e -> scores already in log2 units)
    f32x4 sc[4] = {};
    __builtin_amdgcn_s_setprio(1);
#pragma unroll
    for (int kf = 0; kf < 4; kf++) {
#pragma unroll
      for (int kk = 0; kk < 2; kk++) {
        bf16x8 bk = *reinterpret_cast<const bf16x8*>(kb + offKV[kf * 2 + kk]);
        sc[kf] = MFMA16(aq[kk], bk, sc[kf]);
      }
    }
    __builtin_amdgcn_s_setprio(0);
    // causal mask: diagonal tile only
    if (kvt == qt) {
#pragma unroll
      for (int kf = 0; kf < 4; kf++)
#pragma unroll
        for (int j = 0; j < 4; j++) {
          const int keyl = kf * 16 + fr;
          const int ql = w * 16 + fq * 4 + j;
          if (keyl > ql) sc[kf][j] = -3e38f;
        }
    }
    // online softmax: tile max per row (rows live across fr lanes)
    float mj[4];
#pragma unroll
    for (int j = 0; j < 4; j++) {
      float m = fmaxf(fmaxf(sc[0][j], sc[1][j]), fmaxf(sc[2][j], sc[3][j]));
#pragma unroll
      for (int off = 1; off < 16; off <<= 1)
        m = fmaxf(m, __shfl_xor(m, off, 64));
      mj[j] = m;
    }
    // defer-max: only rescale when a row max grew by > 8 (log2 units)
    const bool need = (mj[0] > mrun[0] + 8.f) | (mj[1] > mrun[1] + 8.f) |
                      (mj[2] > mrun[2] + 8.f) | (mj[3] > mrun[3] + 8.f);
    if (__any((int)need)) {
#pragma unroll
      for (int j = 0; j < 4; j++) {
        const float mnew = fmaxf(mrun[j], mj[j]);
        const float alpha = exp2_fast(mrun[j] - mnew);
        mrun[j] = mnew;
        lpart[j] *= alpha;
#pragma unroll
        for (int df = 0; df < 4; df++) o[df][j] *= alpha;
      }
    }
    // P = exp2(S - m); accumulate per-lane partial row-sums (reduced at flush)
#pragma unroll
    for (int j = 0; j < 4; j++) {
#pragma unroll
      for (int kf = 0; kf < 4; kf++) {
        const float p = exp2_fast(sc[kf][j] - mrun[j]);
        sc[kf][j] = p;
        lpart[j] += p;
      }
    }
    // P -> per-wave LDS (bf16), then read A-fragments (wave-internal DS ordering)
#pragma unroll
    for (int kf = 0; kf < 4; kf++)
#pragma unroll
      for (int j = 0; j < 4; j++)
        myp[(fq * 4 + j) * 72 + kf * 16 + fr] = cvt_bf16_1(sc[kf][j]);
    bf16x8 pa[2];
#pragma unroll
    for (int kk = 0; kk < 2; kk++)
      pa[kk] = *reinterpret_cast<const bf16x8*>(myp + fr * 72 + kk * 32 + fq * 8);
    // O += P V  (V tile in LDS: [d-row][key] swizzled; same offsets as K)
    __builtin_amdgcn_s_setprio(1);
#pragma unroll
    for (int df = 0; df < 4; df++) {
#pragma unroll
      for (int kk = 0; kk < 2; kk++) {
        bf16x8 bv = *reinterpret_cast<const bf16x8*>(vb + offKV[df * 2 + kk]);
        o[df] = MFMA16(pa[kk], bv, o[df]);
      }
    }
    __builtin_amdgcn_s_setprio(0);

    // prefetch tile ti+2 into the buffer being retired at ti-1 (3-buffer ring).
    // Safe: all waves are past this iteration's barrier, so everyone finished
    // reading buf[(ti+2)%3] during iteration ti-1.
    const int nxt = ti + 2;
    if (nxt < nTot) {
      const int bufn = cur >= 1 ? cur - 1 : 2; // (cur+2)%3
      const int nk = KVIDX(nxt);
      STAGE(bufn, nk);
    }
    cur = cur == 2 ? 0 : cur + 1;
  }
  write_out(qtB);
#undef STAGE
#undef KVIDX
}

extern "C" void kernel_launch(void* const* d_in, const int* in_sizes, int n_in,
                              void* d_out, int out_size, void* d_ws, size_t ws_size,
                              hipStream_t stream) {
  const float* x = (const float*)d_in[0];
  const float* Wqkv = (const float*)d_in[1];
  const float* bqkv = (const float*)d_in[2];
  const float* Wout = (const float*)d_in[3];
  const float* bout = (const float*)d_in[4];
  float* out = (float*)d_out;

  char* p = (char*)d_ws;
  u16* xb = (u16*)p;    p += (size_t)MTOK * D * 2;       // 16.8 MB
  u16* wqkvT = (u16*)p; p += (size_t)3 * D * D * 2;      // 6.3 MB
  u16* woutT = (u16*)p; p += (size_t)D * D * 2;          // 2.1 MB
  u16* Qb = (u16*)p;    p += (size_t)BH * SS * HD * 2;   // 16.8 MB
  u16* Kb = (u16*)p;    p += (size_t)BH * SS * HD * 2;   // 16.8 MB
  u16* Vt = (u16*)p;    p += (size_t)BH * SS * HD * 2;   // 16.8 MB
  u16* vals = (u16*)p;  p += (size_t)MTOK * D * 2;       // 16.8 MB  (total ~92 MB)

  cvt_bf16<<<2048, 256, 0, stream>>>(x, xb, MTOK * D / 4);
  transpose_bf16<<<dim3(3 * D / 32, D / 32), dim3(32, 8), 0, stream>>>(Wqkv, wqkvT, D, 3 * D);
  transpose_bf16<<<dim3(D / 32, D / 32), dim3(32, 8), 0, stream>>>(Wout, woutT, D, D);
  gemm_bf16<0><<<dim3(MTOK / 128, 3 * D / 128), 256, 0, stream>>>(
      xb, wqkvT, bqkv, Qb, Kb, Vt, nullptr, MTOK, 3 * D, D);
  attn_fwd<<<dim3(16 * BH), 256, 0, stream>>>(Qb, Kb, Vt, vals);
  gemm_bf16<1><<<dim3(MTOK / 128, D / 128), 256, 0, stream>>>(
      vals, woutT, bout, nullptr, nullptr, nullptr, out, MTOK, D, D);
}

// Round 9
// 204.717 us; speedup vs baseline: 1.2989x; 1.1415x over previous
//
#include <hip/hip_runtime.h>

typedef unsigned short u16;
typedef unsigned int u32;
typedef __attribute__((ext_vector_type(8))) short bf16x8;
typedef __attribute__((ext_vector_type(4))) float f32x4;

#define MFMA16(a, b, c) __builtin_amdgcn_mfma_f32_16x16x32_bf16((a), (b), (c), 0, 0, 0)

constexpr int D = 1024;       // d_model
constexpr int NH = 16;        // heads
constexpr int HD = 64;        // head dim
constexpr int BB = 4;         // batch
constexpr int SS = 2048;      // seq len
constexpr int BH = BB * NH;   // 64
constexpr int MTOK = BB * SS; // 8192
constexpr float SCALE_LOG2E = 0.125f * 1.44269504088896340736f; // HD^-0.5 * log2(e)

__device__ __forceinline__ u16 f32_bf16(float f) {
  union { float f; u32 u; } v; v.f = f;
  u32 u = v.u;
  u += 0x7FFFu + ((u >> 16) & 1u); // RNE
  return (u16)(u >> 16);
}

// single-instruction transcendental / convert paths (avoid ocml calls)
__device__ __forceinline__ float exp2_fast(float x) {
  float r; asm("v_exp_f32 %0, %1" : "=v"(r) : "v"(x)); return r;
}
__device__ __forceinline__ u16 cvt_bf16_1(float f) {
  u32 r; asm("v_cvt_pk_bf16_f32 %0, %1, %1" : "=v"(r) : "v"(f)); return (u16)r;
}

__device__ __forceinline__ void gload_lds16(const void* g, u16* l) {
  __builtin_amdgcn_global_load_lds(
      (const __attribute__((address_space(1))) u32*)g,
      (__attribute__((address_space(3))) u32*)l, 16, 0, 0);
}

// ---------------- fp32 -> bf16 elementwise convert ----------------
__global__ __launch_bounds__(256)
void cvt_bf16(const float* __restrict__ in, u16* __restrict__ out, int n4) {
  int i = blockIdx.x * 256 + threadIdx.x;
  const int stride = gridDim.x * 256;
  for (; i < n4; i += stride) {
    float4 v = reinterpret_cast<const float4*>(in)[i];
    u32 lo = (u32)f32_bf16(v.x) | ((u32)f32_bf16(v.y) << 16);
    u32 hi = (u32)f32_bf16(v.z) | ((u32)f32_bf16(v.w) << 16);
    reinterpret_cast<uint2*>(out)[i] = make_uint2(lo, hi);
  }
}

// ---------------- fp32 [R][C] -> bf16 [C][R] transpose ----------------
__global__ __launch_bounds__(256)
void transpose_bf16(const float* __restrict__ in, u16* __restrict__ out, int R, int C) {
  __shared__ float tile[32][33];
  const int c0 = blockIdx.x * 32, r0 = blockIdx.y * 32;
  const int tx = threadIdx.x, ty = threadIdx.y;
#pragma unroll
  for (int i = 0; i < 4; i++)
    tile[ty + 8 * i][tx] = in[(size_t)(r0 + ty + 8 * i) * C + c0 + tx];
  __syncthreads();
#pragma unroll
  for (int i = 0; i < 4; i++)
    out[(size_t)(c0 + ty + 8 * i) * R + r0 + tx] = f32_bf16(tile[tx][ty + 8 * i]);
}

// ---------------- bf16 GEMM: C[M][N] = A[M][K] * Bt[N][K]^T + bias ----------------
// 2D grid (round-6 measured-good mapping).
// MODE 0: scatter into Q (pre-scaled by SCALE*log2e) [BH][S][64], K [BH][S][64],
//         Vt [BH][64][S] (bf16)
// MODE 1: fp32 out [M][N]
template <int MODE>
__global__ __launch_bounds__(256)
void gemm_bf16(const u16* __restrict__ A, const u16* __restrict__ Bt,
               const float* __restrict__ bias,
               u16* __restrict__ q_out, u16* __restrict__ k_out,
               u16* __restrict__ vt_out, float* __restrict__ f_out,
               int M, int N, int K) {
  constexpr int BK = 32;
  __shared__ u16 lds_a[128 * BK];
  __shared__ u16 lds_b[128 * BK];
  const int m0 = blockIdx.x * 128;
  const int n0 = blockIdx.y * 128;
  const int t = threadIdx.x;
  const int lane = t & 63;
  const int w = t >> 6;
  const int wr = w >> 1, wc = w & 1;        // 2x2 wave grid, 64x64 per wave
  const int fr = lane & 15, fq = lane >> 4; // fragment row/col group

  const u16* ga0 = A + (size_t)(m0 + (t >> 2)) * K + (t & 3) * 8;
  const u16* ga1 = ga0 + (size_t)64 * K;
  const u16* gb0 = Bt + (size_t)(n0 + (t >> 2)) * K + (t & 3) * 8;
  const u16* gb1 = gb0 + (size_t)64 * K;
  u16* la0 = lds_a + t * 8;
  u16* la1 = lds_a + (t + 256) * 8;
  u16* lb0 = lds_b + t * 8;
  u16* lb1 = lds_b + (t + 256) * 8;

  f32x4 acc[4][4] = {};

  for (int k0 = 0; k0 < K; k0 += BK) {
    __syncthreads();
    gload_lds16(ga0, la0);
    gload_lds16(ga1, la1);
    gload_lds16(gb0, lb0);
    gload_lds16(gb1, lb1);
    ga0 += BK; ga1 += BK; gb0 += BK; gb1 += BK;
    __syncthreads();
    bf16x8 af[4], bfr[4];
#pragma unroll
    for (int i = 0; i < 4; i++)
      af[i] = *reinterpret_cast<const bf16x8*>(lds_a + (wr * 64 + i * 16 + fr) * BK + fq * 8);
#pragma unroll
    for (int i = 0; i < 4; i++)
      bfr[i] = *reinterpret_cast<const bf16x8*>(lds_b + (wc * 64 + i * 16 + fr) * BK + fq * 8);
#pragma unroll
    for (int i = 0; i < 4; i++)
#pragma unroll
      for (int j = 0; j < 4; j++)
        acc[i][j] = MFMA16(af[i], bfr[j], acc[i][j]);
  }

#pragma unroll
  for (int i = 0; i < 4; i++) {
#pragma unroll
    for (int j = 0; j < 4; j++) {
      const int ncol = n0 + wc * 64 + j * 16 + fr;
      const float bs = bias[ncol];
#pragma unroll
      for (int r = 0; r < 4; r++) {
        const int mrow = m0 + wr * 64 + i * 16 + fq * 4 + r;
        const float vv = acc[i][j][r] + bs;
        if (MODE == 0) {
          const int which = ncol >> 10;
          const int rem = ncol & 1023;
          const int hh = rem >> 6, dd = rem & 63;
          const int bb = mrow >> 11, ss = mrow & 2047;
          const int bh = bb * 16 + hh;
          if (which == 0)
            q_out[((size_t)bh * SS + ss) * HD + dd] = f32_bf16(vv * SCALE_LOG2E);
          else if (which == 1)
            k_out[((size_t)bh * SS + ss) * HD + dd] = f32_bf16(vv);
          else
            vt_out[((size_t)bh * HD + dd) * SS + ss] = f32_bf16(vv);
        } else {
          f_out[(size_t)mrow * N + ncol] = vv;
        }
      }
    }
  }
}

// ---------------- causal flash attention ----------------
// Q (pre-scaled), K: [BH][S][64] bf16 ; Vt: [BH][64][S] bf16 ; vals: [B][S][D] bf16
// QBLK=128: 8 waves/block (512 thr), 16 q-rows per wave. Block = q-tile PAIR
// (pA, 15-pA): uniform 34 kv-iterations. 512 blocks = 2/CU -> 16 waves/CU
// (2x round-8 TLP; round-8 showed the limiter is latency-hiding, not pipeline
// depth). XCD swizzle: 8 heads/XCD = 4MB K/V L2-resident (verified FETCH drop).
// 3-buffer ring, 2-deep prefetch, counted vmcnt (2 loads/thread/tile).
// nA = 2*qtA+2 >= 2 so the prologue STAGE(1, kv=1) is always correct (fixes
// round-8's pi==0 mis-stage that pushed absmax to 0.072).
__global__ __launch_bounds__(512)
void attn_fwd(const u16* __restrict__ Qb, const u16* __restrict__ Kb,
              const u16* __restrict__ Vt, u16* __restrict__ vals) {
  const int bid = blockIdx.x;                 // 0..511
  const int wk = (bid & 7) * 64 + (bid >> 3); // XCD-contiguous chunks of 64
  const int bh = wk >> 3;                     // 8 heads per XCD chunk
  const int pA = wk & 7;
  const int qtA = pA, qtB = 15 - pA;          // 128-row q-tiles
  const int nA = 2 * qtA + 2;                 // kv tiles for segment A
  const int nTot = 34;                        // nA + 2*qtB+2 == 34 uniform
  const u16* Qp = Qb + (size_t)bh * SS * HD;
  const char* Kp = (const char*)(Kb + (size_t)bh * SS * HD);
  const char* Vp = (const char*)(Vt + (size_t)bh * HD * SS);
  const int t = threadIdx.x, lane = t & 63, w = t >> 6; // w 0..7
  const int fr = lane & 15, fq = lane >> 4;
  const int swz = (fr & 7) << 4;

  __shared__ u16 kbuf[3][4096]; // [64 kv-rows][128B] swizzled, 8KB each
  __shared__ u16 vbuf[3][4096]; // [64 d-rows][128B keys] swizzled
  __shared__ u16 plds[8][16][72];
  u16* myp = &plds[w][0][0];

  const int lin = t * 16; // staging byte offset: 512 thr x 16B = 8KB tile

  // loop-invariant swizzled LDS fragment offsets (static-indexed -> registers)
  int offKV[8];
#pragma unroll
  for (int kf = 0; kf < 4; kf++)
#pragma unroll
    for (int kk = 0; kk < 2; kk++)
      offKV[kf * 2 + kk] = (kf * 16 + fr) * 128 + ((kk * 64 + fq * 16) ^ swz);

  bf16x8 aq[2];
  {
    const int qbase = qtA * 128 + w * 16;
#pragma unroll
    for (int kk = 0; kk < 2; kk++)
      aq[kk] = *reinterpret_cast<const bf16x8*>(Qp + (size_t)(qbase + fr) * HD + kk * 32 + fq * 8);
  }

  f32x4 o[4] = {};
  float mrun[4], lpart[4];
#pragma unroll
  for (int j = 0; j < 4; j++) { mrun[j] = -3e38f; lpart[j] = 0.f; }

#define STAGE(bufi, kvt_)                                                     \
  {                                                                           \
    const int row = lin >> 7, colb = lin & 127;                               \
    const int scol = colb ^ ((row & 7) << 4);                                 \
    gload_lds16(Kp + (size_t)((kvt_) * 64 + row) * 128 + scol,                \
                &kbuf[bufi][lin >> 1]);                                       \
    gload_lds16(Vp + (size_t)row * 4096 + (kvt_) * 128 + scol,                \
                &vbuf[bufi][lin >> 1]);                                       \
  }
#define KVIDX(ti_) ((ti_) >= nA ? (ti_) - nA : (ti_))

  auto write_out = [&](int qt) {
    const int b_ = bh >> 4, h_ = bh & 15;
    const int qb = qt * 128 + w * 16;
    float linv[4];
#pragma unroll
    for (int j = 0; j < 4; j++) {
      float rs = lpart[j];
#pragma unroll
      for (int off = 1; off < 16; off <<= 1)
        rs += __shfl_xor(rs, off, 64);
      linv[j] = 1.f / rs;
    }
#pragma unroll
    for (int df = 0; df < 4; df++)
#pragma unroll
      for (int j = 0; j < 4; j++) {
        const float vv = o[df][j] * linv[j];
        const int qg = qb + fq * 4 + j;
        vals[((size_t)(b_ * SS + qg)) * D + h_ * HD + df * 16 + fr] = cvt_bf16_1(vv);
      }
  };

  int cur = 0;
  STAGE(0, 0);
  STAGE(1, 1); // nA >= 2 always, so kv tile 1 of segment A is correct

  for (int ti = 0; ti < nTot; ++ti) {
    const bool segB = ti >= nA;
    const int kvt = segB ? ti - nA : ti;
    const int qt = segB ? qtB : qtA;

    // wait for tile ti's 2 loads; keep tile ti+1's 2 in flight (counted vmcnt)
    if (ti + 1 < nTot)
      asm volatile("s_waitcnt vmcnt(2)" ::: "memory");
    else
      asm volatile("s_waitcnt vmcnt(0)" ::: "memory");
    __builtin_amdgcn_s_barrier();
    __builtin_amdgcn_sched_barrier(0);

    if (ti == nA) { // segment switch: flush A, reset state for B
      write_out(qtA);
      const int qbase = qtB * 128 + w * 16;
#pragma unroll
      for (int kk = 0; kk < 2; kk++)
        aq[kk] = *reinterpret_cast<const bf16x8*>(Qp + (size_t)(qbase + fr) * HD + kk * 32 + fq * 8);
#pragma unroll
      for (int j = 0; j < 4; j++) { mrun[j] = -3e38f; lpart[j] = 0.f; }
#pragma unroll
      for (int df = 0; df < 4; df++) o[df] = f32x4{0.f, 0.f, 0.f, 0.f};
    }

    const char* kb = (const char*)kbuf[cur];
    const char* vb = (const char*)vbuf[cur];

    // S = Q K^T (Q pre-scaled by SCALE*log2e -> scores already in log2 units)
    f32x4 sc[4] = {};
    __builtin_amdgcn_s_setprio(1);
#pragma unroll
    for (int kf = 0; kf < 4; kf++) {
#pragma unroll
      for (int kk = 0; kk < 2; kk++) {
        bf16x8 bk = *reinterpret_cast<const bf16x8*>(kb + offKV[kf * 2 + kk]);
        sc[kf] = MFMA16(aq[kk], bk, sc[kf]);
      }
    }
    __builtin_amdgcn_s_setprio(0);
    // causal mask: the two kv tiles straddling this q-tile's diagonal
    if ((kvt >> 1) == qt) {
      const int kg0 = kvt * 64 + fr;
      const int rg0 = qt * 128 + w * 16 + fq * 4;
#pragma unroll
      for (int kf = 0; kf < 4; kf++)
#pragma unroll
        for (int j = 0; j < 4; j++)
          if (kg0 + kf * 16 > rg0 + j) sc[kf][j] = -3e38f;
    }
    // online softmax: tile max per row (rows live across fr lanes)
    float mj[4];
#pragma unroll
    for (int j = 0; j < 4; j++) {
      float m = fmaxf(fmaxf(sc[0][j], sc[1][j]), fmaxf(sc[2][j], sc[3][j]));
#pragma unroll
      for (int off = 1; off < 16; off <<= 1)
        m = fmaxf(m, __shfl_xor(m, off, 64));
      mj[j] = m;
    }
    // defer-max: only rescale when a row max grew by > 8 (log2 units)
    const bool need = (mj[0] > mrun[0] + 8.f) | (mj[1] > mrun[1] + 8.f) |
                      (mj[2] > mrun[2] + 8.f) | (mj[3] > mrun[3] + 8.f);
    if (__any((int)need)) {
#pragma unroll
      for (int j = 0; j < 4; j++) {
        const float mnew = fmaxf(mrun[j], mj[j]);
        const float alpha = exp2_fast(mrun[j] - mnew);
        mrun[j] = mnew;
        lpart[j] *= alpha;
#pragma unroll
        for (int df = 0; df < 4; df++) o[df][j] *= alpha;
      }
    }
    // P = exp2(S - m); accumulate per-lane partial row-sums (reduced at flush)
#pragma unroll
    for (int j = 0; j < 4; j++) {
#pragma unroll
      for (int kf = 0; kf < 4; kf++) {
        const float p = exp2_fast(sc[kf][j] - mrun[j]);
        sc[kf][j] = p;
        lpart[j] += p;
      }
    }
    // P -> per-wave LDS (bf16), then read A-fragments (wave-internal DS ordering)
#pragma unroll
    for (int kf = 0; kf < 4; kf++)
#pragma unroll
      for (int j = 0; j < 4; j++)
        myp[(fq * 4 + j) * 72 + kf * 16 + fr] = cvt_bf16_1(sc[kf][j]);
    bf16x8 pa[2];
#pragma unroll
    for (int kk = 0; kk < 2; kk++)
      pa[kk] = *reinterpret_cast<const bf16x8*>(myp + fr * 72 + kk * 32 + fq * 8);
    // O += P V  (V tile in LDS: [d-row][key] swizzled; same offsets as K)
    __builtin_amdgcn_s_setprio(1);
#pragma unroll
    for (int df = 0; df < 4; df++) {
#pragma unroll
      for (int kk = 0; kk < 2; kk++) {
        bf16x8 bv = *reinterpret_cast<const bf16x8*>(vb + offKV[df * 2 + kk]);
        o[df] = MFMA16(pa[kk], bv, o[df]);
      }
    }
    __builtin_amdgcn_s_setprio(0);

    // prefetch tile ti+2 into the buffer retired at ti-1 (3-buffer ring);
    // safe: all waves passed this iteration's barrier
    const int nxt = ti + 2;
    if (nxt < nTot) {
      const int bufn = cur >= 1 ? cur - 1 : 2; // (cur+2)%3
      STAGE(bufn, KVIDX(nxt));
    }
    cur = cur == 2 ? 0 : cur + 1;
  }
  write_out(qtB);
#undef STAGE
#undef KVIDX
}

extern "C" void kernel_launch(void* const* d_in, const int* in_sizes, int n_in,
                              void* d_out, int out_size, void* d_ws, size_t ws_size,
                              hipStream_t stream) {
  const float* x = (const float*)d_in[0];
  const float* Wqkv = (const float*)d_in[1];
  const float* bqkv = (const float*)d_in[2];
  const float* Wout = (const float*)d_in[3];
  const float* bout = (const float*)d_in[4];
  float* out = (float*)d_out;

  char* p = (char*)d_ws;
  u16* xb = (u16*)p;    p += (size_t)MTOK * D * 2;       // 16.8 MB
  u16* wqkvT = (u16*)p; p += (size_t)3 * D * D * 2;      // 6.3 MB
  u16* woutT = (u16*)p; p += (size_t)D * D * 2;          // 2.1 MB
  u16* Qb = (u16*)p;    p += (size_t)BH * SS * HD * 2;   // 16.8 MB
  u16* Kb = (u16*)p;    p += (size_t)BH * SS * HD * 2;   // 16.8 MB
  u16* Vt = (u16*)p;    p += (size_t)BH * SS * HD * 2;   // 16.8 MB
  u16* vals = (u16*)p;  p += (size_t)MTOK * D * 2;       // 16.8 MB  (total ~92 MB)

  cvt_bf16<<<2048, 256, 0, stream>>>(x, xb, MTOK * D / 4);
  transpose_bf16<<<dim3(3 * D / 32, D / 32), dim3(32, 8), 0, stream>>>(Wqkv, wqkvT, D, 3 * D);
  transpose_bf16<<<dim3(D / 32, D / 32), dim3(32, 8), 0, stream>>>(Wout, woutT, D, D);
  gemm_bf16<0><<<dim3(MTOK / 128, 3 * D / 128), 256, 0, stream>>>(
      xb, wqkvT, bqkv, Qb, Kb, Vt, nullptr, MTOK, 3 * D, D);
  attn_fwd<<<dim3(512), 512, 0, stream>>>(Qb, Kb, Vt, vals);
  gemm_bf16<1><<<dim3(MTOK / 128, D / 128), 256, 0, stream>>>(
      vals, woutT, bout, nullptr, nullptr, nullptr, out, MTOK, D, D);
}